// Round 6
// baseline (267.052 us; speedup 1.0000x reference)
//
#include <hip/hip_runtime.h>
#include <hip/hip_bf16.h>

typedef __bf16 bf16;
typedef _Float16 f16;
typedef bf16 bf16x8 __attribute__((ext_vector_type(8)));
typedef bf16 bf16x4 __attribute__((ext_vector_type(4)));
typedef f16 f16x4 __attribute__((ext_vector_type(4)));
typedef float f32x4 __attribute__((ext_vector_type(4)));

#define SLEN 2048
#define HEADS 12
#define DMODEL 768

// async global->LDS, 16B per lane; lds base must be wave-uniform (HW scatters lane*16)
#define GLOAD16(g, l) \
    __builtin_amdgcn_global_load_lds((const __attribute__((address_space(1))) void*)(g), \
                                     (__attribute__((address_space(3))) void*)(l), 16, 0, 0)

// ---------------- fp32 -> bf16 convert ----------------
__global__ void cvt_kernel(const float* __restrict__ src, bf16* __restrict__ dst, int n4) {
    int idx = blockIdx.x * blockDim.x + threadIdx.x;
    if (idx < n4) {
        float4 v = ((const float4*)src)[idx];
        bf16x4 o;
        o[0] = (bf16)v.x; o[1] = (bf16)v.y; o[2] = (bf16)v.z; o[3] = (bf16)v.w;
        *(bf16x4*)(dst + (size_t)idx * 4) = o;
    }
}

__global__ void cvt4_kernel(const float* __restrict__ s0, const float* __restrict__ s1,
                            const float* __restrict__ s2, const float* __restrict__ s3,
                            bf16* __restrict__ d0, bf16* __restrict__ d1,
                            bf16* __restrict__ d2, bf16* __restrict__ d3, int n4) {
    const float* s; bf16* d;
    switch (blockIdx.y) {
        case 0: s = s0; d = d0; break;
        case 1: s = s1; d = d1; break;
        case 2: s = s2; d = d2; break;
        default: s = s3; d = d3; break;
    }
    int idx = blockIdx.x * blockDim.x + threadIdx.x;
    if (idx < n4) {
        float4 v = ((const float4*)s)[idx];
        bf16x4 o;
        o[0] = (bf16)v.x; o[1] = (bf16)v.y; o[2] = (bf16)v.z; o[3] = (bf16)v.w;
        *(bf16x4*)(d + (size_t)idx * 4) = o;
    }
}

// ---------------- QKV projection GEMM: 128x256 block, 64x128 wave tile ----------------
// Wave tile 64x128 -> 42.7 FLOP per LDS byte (vs 32 at 64x64): raises the
// ds_read_b128 ceiling from ~34% to ~46% MfmaUtil. C^T orientation epilogue.
__global__ __launch_bounds__(256, 2) void gemm_qkv(
    const bf16* __restrict__ A, const bf16* __restrict__ Bw,
    const float* __restrict__ bq, const float* __restrict__ bk, const float* __restrict__ bv,
    bf16* __restrict__ Qb, bf16* __restrict__ Kb, f16* __restrict__ VTb)
{
    __shared__ __align__(16) char smem[49152];   // As[2] 16KB + Bs[2] 32KB; Cs aliases (33.8KB)
    typedef bf16 ATile[128][32];
    typedef bf16 BTile[256][32];
    ATile* As = (ATile*)smem;
    BTile* Bs = (BTile*)(smem + 16384);
    const int K = DMODEL;
    int tid = threadIdx.x;
    int w = tid >> 6, lane = tid & 63, i16 = lane & 15, q4 = lane >> 4;
    int mblk = (w & 1) * 64, nblk = (w >> 1) * 128;
    int row0 = blockIdx.y * 128, col0 = blockIdx.x * 256;
    int srow = lane >> 2, scol = (lane & 3) * 8;
    f32x4 acc[8][4] = {};   // acc[ct][st] = C^T: out-col tile x s tile

    const bf16* Ab = A  + (size_t)(row0 + w * 16 + srow) * K + scol;
    const bf16* Bb = Bw + (size_t)(col0 + w * 16 + srow) * K + scol;

#define STAGE(buf, k0) do { \
        GLOAD16(Ab + (k0),                   &As[buf][w * 16][0]); \
        GLOAD16(Ab + (size_t)64 * K + (k0),  &As[buf][w * 16 + 64][0]); \
        GLOAD16(Bb + (k0),                   &Bs[buf][w * 16][0]); \
        GLOAD16(Bb + (size_t)64 * K + (k0),  &Bs[buf][w * 16 + 64][0]); \
        GLOAD16(Bb + (size_t)128 * K + (k0), &Bs[buf][w * 16 + 128][0]); \
        GLOAD16(Bb + (size_t)192 * K + (k0), &Bs[buf][w * 16 + 192][0]); \
    } while (0)

    STAGE(0, 0);
    __syncthreads();
    int buf = 0;
    for (int k0 = 0; k0 < K; k0 += 32, buf ^= 1) {
        if (k0 + 32 < K) STAGE(buf ^ 1, k0 + 32);
        bf16x8 af[4], bfr[8];
#pragma unroll
        for (int t = 0; t < 4; ++t) af[t]  = *(const bf16x8*)(&As[buf][mblk + t * 16 + i16][q4 * 8]);
#pragma unroll
        for (int t = 0; t < 8; ++t) bfr[t] = *(const bf16x8*)(&Bs[buf][nblk + t * 16 + i16][q4 * 8]);
#pragma unroll
        for (int ct = 0; ct < 8; ++ct)
#pragma unroll
            for (int st = 0; st < 4; ++st)
                acc[ct][st] = __builtin_amdgcn_mfma_f32_16x16x32_bf16(bfr[ct], af[st], acc[ct][st], 0, 0, 0);
        __syncthreads();
    }
#undef STAGE

    int region = col0 / DMODEL;        // uniform per block (768 = 3*256)
    int cbase = col0 - region * DMODEL + nblk;

    if (region < 2) {
        const float* bias = region ? bk : bq;
        bf16* dstb = region ? Kb : Qb;
#pragma unroll
        for (int ct = 0; ct < 8; ++ct) {
#pragma unroll
            for (int st = 0; st < 4; ++st) {
                int c0 = cbase + ct * 16 + q4 * 4;
                int h = c0 >> 6, d0 = c0 & 63;
                int sg = row0 + mblk + st * 16 + i16;
                int b = sg >> 11, s = sg & 2047;
                float4 bb = *(const float4*)(bias + c0);
                bf16x4 o;
                if (region == 0) {
                    o[0] = (bf16)((acc[ct][st][0] + bb.x) * 0.0225421217f);  // (1/64)*log2(e)
                    o[1] = (bf16)((acc[ct][st][1] + bb.y) * 0.0225421217f);
                    o[2] = (bf16)((acc[ct][st][2] + bb.z) * 0.0225421217f);
                    o[3] = (bf16)((acc[ct][st][3] + bb.w) * 0.0225421217f);
                } else {
                    o[0] = (bf16)(acc[ct][st][0] + bb.x);
                    o[1] = (bf16)(acc[ct][st][1] + bb.y);
                    o[2] = (bf16)(acc[ct][st][2] + bb.z);
                    o[3] = (bf16)(acc[ct][st][3] + bb.w);
                }
                *(bf16x4*)(dstb + (((size_t)(b * HEADS + h)) * SLEN + s) * 64 + d0) = o;
            }
        }
    } else {
        // V: two 128-col passes through an LDS transpose, coalesced 16B V^T stores
        f16 (*Cs)[132] = (f16(*)[132])smem;
#pragma unroll
        for (int p = 0; p < 2; ++p) {
            if ((w >> 1) == p) {
#pragma unroll
                for (int ct = 0; ct < 8; ++ct) {
#pragma unroll
                    for (int st = 0; st < 4; ++st) {
                        int cg = cbase + ct * 16 + q4 * 4;
                        float4 bb = *(const float4*)(bv + cg);
                        f16x4 vv;
                        vv[0] = (f16)(acc[ct][st][0] + bb.x);
                        vv[1] = (f16)(acc[ct][st][1] + bb.y);
                        vv[2] = (f16)(acc[ct][st][2] + bb.z);
                        vv[3] = (f16)(acc[ct][st][3] + bb.w);
                        *(f16x4*)(&Cs[mblk + st * 16 + i16][ct * 16 + q4 * 4]) = vv;
                    }
                }
            }
            __syncthreads();
            int cl = lane * 2;
            int cg = (col0 - 2 * DMODEL) + p * 128 + cl;
            int h = cg >> 6, d = cg & 63;
            int s0 = w * 32;
            int b = row0 >> 11, sg = (row0 & 2047) + s0;
            f16* dst0 = VTb + ((size_t)(b * HEADS + h) * 64 + d) * SLEN + sg;
            f16* dst1 = dst0 + SLEN;
#pragma unroll
            for (int j = 0; j < 4; ++j) {
                unsigned v[8];
#pragma unroll
                for (int i = 0; i < 8; ++i) v[i] = *(const unsigned*)(&Cs[s0 + j * 8 + i][cl]);
                unsigned lo[4], hi[4];
#pragma unroll
                for (int i = 0; i < 4; ++i) {
                    lo[i] = (v[2 * i] & 0xffffu) | (v[2 * i + 1] << 16);
                    hi[i] = (v[2 * i] >> 16) | (v[2 * i + 1] & 0xffff0000u);
                }
                *(uint4*)(dst0 + j * 8) = *(uint4*)lo;
                *(uint4*)(dst1 + j * 8) = *(uint4*)hi;
            }
            __syncthreads();
        }
    }
}

// ---------------- output projection GEMM (R5: 128x128, C^T, float4 stores) ----------------
__global__ __launch_bounds__(256, 3) void gemm_out(
    const bf16* __restrict__ A, const bf16* __restrict__ Bw,
    const float* __restrict__ bo, float* __restrict__ out)
{
    __shared__ bf16 As[2][128][32];
    __shared__ bf16 Bs[2][128][32];
    const int K = DMODEL;
    int tid = threadIdx.x;
    int w = tid >> 6, lane = tid & 63, i16 = lane & 15, q4 = lane >> 4;
    int mblk = (w & 1) * 64, nblk = (w >> 1) * 64;
    int row0 = blockIdx.y * 128, col0 = blockIdx.x * 128;
    int srow = (lane >> 2), scol = (lane & 3) * 8;
    f32x4 acc[4][4] = {};

    const bf16* Ab = A  + (size_t)(row0 + w * 16 + srow) * K + scol;
    const bf16* Bb = Bw + (size_t)(col0 + w * 16 + srow) * K + scol;

#define STAGE(buf, k0) do { \
        GLOAD16(Ab + (k0),                  &As[buf][w * 16][0]); \
        GLOAD16(Ab + (size_t)64 * K + (k0), &As[buf][w * 16 + 64][0]); \
        GLOAD16(Bb + (k0),                  &Bs[buf][w * 16][0]); \
        GLOAD16(Bb + (size_t)64 * K + (k0), &Bs[buf][w * 16 + 64][0]); \
    } while (0)

    STAGE(0, 0);
    __syncthreads();
    int buf = 0;
    for (int k0 = 0; k0 < K; k0 += 32, buf ^= 1) {
        if (k0 + 32 < K) STAGE(buf ^ 1, k0 + 32);
        bf16x8 af[4], bfr[4];
#pragma unroll
        for (int t = 0; t < 4; ++t) af[t] = *(const bf16x8*)(&As[buf][mblk + t * 16 + i16][q4 * 8]);
#pragma unroll
        for (int t = 0; t < 4; ++t) bfr[t] = *(const bf16x8*)(&Bs[buf][nblk + t * 16 + i16][q4 * 8]);
#pragma unroll
        for (int ct = 0; ct < 4; ++ct)
#pragma unroll
            for (int st = 0; st < 4; ++st)
                acc[ct][st] = __builtin_amdgcn_mfma_f32_16x16x32_bf16(bfr[ct], af[st], acc[ct][st], 0, 0, 0);
        __syncthreads();
    }
#undef STAGE

#pragma unroll
    for (int ct = 0; ct < 4; ++ct) {
#pragma unroll
        for (int st = 0; st < 4; ++st) {
            int c0 = col0 + nblk + ct * 16 + q4 * 4;
            int s = row0 + mblk + st * 16 + i16;
            float4 bb = *(const float4*)(bo + c0);
            float4 o = {acc[ct][st][0] + bb.x, acc[ct][st][1] + bb.y,
                        acc[ct][st][2] + bb.z, acc[ct][st][3] + bb.w};
            *(float4*)(out + (size_t)s * DMODEL + c0) = o;
        }
    }
}

// ---------------- flash attention v5: 64 Q-rows/wave (256/block) ----------------
// K/V LDS traffic, staging barriers, and conflicts halve per unit work vs 32/wave.
// VGPR ~150 -> launch_bounds(256,2) (hard lesson R4: never under-budget the cap).
__global__ __launch_bounds__(256, 2) void attn_kernel(
    const bf16* __restrict__ Qb, const bf16* __restrict__ Kb,
    const f16* __restrict__ VTb, bf16* __restrict__ att)
{
    __shared__ bf16 Ks[128][72];   // [key][d], +8 pad
    __shared__ f16  Vt[64][136];   // [d][key], +8 pad

    int tid = threadIdx.x;
    int w = tid >> 6, lane = tid & 63, i16 = lane & 15, q4 = lane >> 4;
    int qt = blockIdx.x, h = blockIdx.y, b = blockIdx.z;
    size_t bh = (size_t)b * HEADS + h;
    const bf16* Qp = Qb + (bh * SLEN + qt * 256 + w * 64) * 64;
    const bf16* Kp = Kb + bh * SLEN * 64;
    const f16*  Vp = VTb + bh * 64 * SLEN;

    bf16x8 aq[4][2];
#pragma unroll
    for (int qs = 0; qs < 4; ++qs) {
        aq[qs][0] = *(const bf16x8*)(Qp + (qs * 16 + i16) * 64 + q4 * 8);
        aq[qs][1] = *(const bf16x8*)(Qp + (qs * 16 + i16) * 64 + 32 + q4 * 8);
    }

    f32x4 oacc[4][4] = {};   // [qs][dt]: O^T, d = dt*16 + q4*4 + r, qrow = i16
    float lsum[4] = {0.f, 0.f, 0.f, 0.f};

    for (int kt = 0; kt < 16; ++kt) {
        int k0 = kt * 128;
        __syncthreads();
#pragma unroll
        for (int it = 0; it < 4; ++it) {
            int cidx = it * 256 + tid;
            int key = cidx >> 3, c8 = cidx & 7;
            *(uint4*)(&Ks[key][c8 * 8]) = *(const uint4*)(Kp + (size_t)(k0 + key) * 64 + c8 * 8);
            int d = cidx >> 4, c16 = cidx & 15;
            *(uint4*)(&Vt[d][c16 * 8]) = *(const uint4*)(Vp + (size_t)d * SLEN + k0 + c16 * 8);
        }
        __syncthreads();

#pragma unroll
        for (int t = 0; t < 8; ++t) {
            bf16x8 kf0 = *(const bf16x8*)(&Ks[t * 16 + i16][q4 * 8]);
            bf16x8 kf1 = *(const bf16x8*)(&Ks[t * 16 + i16][32 + q4 * 8]);
            f16x4 pf[4];
#pragma unroll
            for (int qs = 0; qs < 4; ++qs) {
                f32x4 z = {};
                z = __builtin_amdgcn_mfma_f32_16x16x32_bf16(kf0, aq[qs][0], z, 0, 0, 0);
                z = __builtin_amdgcn_mfma_f32_16x16x32_bf16(kf1, aq[qs][1], z, 0, 0, 0);
#pragma unroll
                for (int r = 0; r < 4; ++r) {
                    float e = __builtin_amdgcn_exp2f(z[r]);
                    lsum[qs] += e;
                    pf[qs][r] = (f16)e;
                }
            }
#pragma unroll
            for (int dt = 0; dt < 4; ++dt) {
                f16x4 vf = *(const f16x4*)(&Vt[dt * 16 + i16][t * 16 + q4 * 4]);
#pragma unroll
                for (int qs = 0; qs < 4; ++qs)
                    oacc[qs][dt] = __builtin_amdgcn_mfma_f32_16x16x16f16(vf, pf[qs], oacc[qs][dt], 0, 0, 0);
            }
        }
    }

#pragma unroll
    for (int qs = 0; qs < 4; ++qs) {
        float l = lsum[qs];
        l += __shfl_xor(l, 16);
        l += __shfl_xor(l, 32);
        float inv = 1.f / l;
        int row = qt * 256 + w * 64 + qs * 16 + i16;
        size_t obase = ((size_t)b * SLEN + row) * DMODEL + h * 64;
#pragma unroll
        for (int dt = 0; dt < 4; ++dt) {
            bf16x4 o;
#pragma unroll
            for (int r = 0; r < 4; ++r) o[r] = (bf16)(oacc[qs][dt][r] * inv);
            *(bf16x4*)(att + obase + dt * 16 + q4 * 4) = o;
        }
    }
}

// ---------------- launch ----------------
extern "C" void kernel_launch(void* const* d_in, const int* in_sizes, int n_in,
                              void* d_out, int out_size, void* d_ws, size_t ws_size,
                              hipStream_t stream) {
    const float* x  = (const float*)d_in[0];
    const float* Wq = (const float*)d_in[1];
    const float* bq = (const float*)d_in[2];
    const float* Wk = (const float*)d_in[3];
    const float* bk = (const float*)d_in[4];
    const float* Wv = (const float*)d_in[5];
    const float* bv = (const float*)d_in[6];
    const float* Wo = (const float*)d_in[7];
    const float* bo = (const float*)d_in[8];
    float* out = (float*)d_out;

    char* ws = (char*)d_ws;
    bf16* xb   = (bf16*)(ws);
    bf16* wqkv = (bf16*)(ws + 12582912);
    bf16* wob  = (bf16*)(ws + 16121856);
    bf16* Qb   = (bf16*)(ws + 17301504);
    bf16* Kb   = (bf16*)(ws + 29884416);
    f16*  VTb  = (f16*)(ws + 42467328);
    bf16* attb = xb;  // xb dead after gemm_qkv; reuse for attention output

    cvt_kernel<<<6144, 256, 0, stream>>>(x, xb, 1572864);
    cvt4_kernel<<<dim3(576, 4), 256, 0, stream>>>(Wq, Wk, Wv, Wo,
                                                  wqkv, wqkv + 589824, wqkv + 1179648, wob, 147456);

    gemm_qkv<<<dim3(9, 64), 256, 0, stream>>>(xb, wqkv, bq, bk, bv, Qb, Kb, VTb);
    attn_kernel<<<dim3(8, 12, 4), 256, 0, stream>>>(Qb, Kb, VTb, attb);
    gemm_out<<<dim3(6, 64), 256, 0, stream>>>(attb, wob, bo, out);
}

// Round 8
// 234.517 us; speedup vs baseline: 1.1387x; 1.1387x over previous
//
#include <hip/hip_runtime.h>
#include <hip/hip_bf16.h>

typedef __bf16 bf16;
typedef _Float16 f16;
typedef bf16 bf16x8 __attribute__((ext_vector_type(8)));
typedef bf16 bf16x4 __attribute__((ext_vector_type(4)));
typedef f16 f16x4 __attribute__((ext_vector_type(4)));
typedef f16 f16x2 __attribute__((ext_vector_type(2)));
typedef float f32x4 __attribute__((ext_vector_type(4)));

#define SLEN 2048
#define HEADS 12
#define DMODEL 768

// async global->LDS, 16B per lane; lds base must be wave-uniform (HW scatters lane*16)
#define GLOAD16(g, l) \
    __builtin_amdgcn_global_load_lds((const __attribute__((address_space(1))) void*)(g), \
                                     (__attribute__((address_space(3))) void*)(l), 16, 0, 0)

// ---------------- fused fp32 -> bf16 convert (x + all 4 weights, one launch) ----------------
__global__ void cvt_all(const float* __restrict__ x,
                        const float* __restrict__ Wq, const float* __restrict__ Wk,
                        const float* __restrict__ Wv, const float* __restrict__ Wo,
                        bf16* __restrict__ xb, bf16* __restrict__ wdst) {
    int idx = blockIdx.x * 256 + threadIdx.x;
    const float* s; bf16* d;
    if (idx < 1572864) {
        s = x; d = xb;
    } else {
        int t = idx - 1572864;
        int wi = t / 147456;          // 0..3 (block-uniform: boundaries on 576-block lines)
        idx = t - wi * 147456;
        s = (wi == 0) ? Wq : (wi == 1) ? Wk : (wi == 2) ? Wv : Wo;
        d = wdst + (size_t)wi * 589824;
    }
    float4 v = ((const float4*)s)[idx];
    bf16x4 o;
    o[0] = (bf16)v.x; o[1] = (bf16)v.y; o[2] = (bf16)v.z; o[3] = (bf16)v.w;
    *(bf16x4*)(d + (size_t)idx * 4) = o;
}

// ---------------- QKV projection GEMM: 128x256 block, 64x128 wave tile ----------------
__global__ __launch_bounds__(256, 2) void gemm_qkv(
    const bf16* __restrict__ A, const bf16* __restrict__ Bw,
    const float* __restrict__ bq, const float* __restrict__ bk, const float* __restrict__ bv,
    bf16* __restrict__ Qb, bf16* __restrict__ Kb, f16* __restrict__ VTb)
{
    __shared__ __align__(16) char smem[49152];
    typedef bf16 ATile[128][32];
    typedef bf16 BTile[256][32];
    ATile* As = (ATile*)smem;
    BTile* Bs = (BTile*)(smem + 16384);
    const int K = DMODEL;
    int tid = threadIdx.x;
    int w = tid >> 6, lane = tid & 63, i16 = lane & 15, q4 = lane >> 4;
    int mblk = (w & 1) * 64, nblk = (w >> 1) * 128;
    int row0 = blockIdx.y * 128, col0 = blockIdx.x * 256;
    int srow = lane >> 2, scol = (lane & 3) * 8;
    f32x4 acc[8][4] = {};

    const bf16* Ab = A  + (size_t)(row0 + w * 16 + srow) * K + scol;
    const bf16* Bb = Bw + (size_t)(col0 + w * 16 + srow) * K + scol;

#define STAGE(buf, k0) do { \
        GLOAD16(Ab + (k0),                   &As[buf][w * 16][0]); \
        GLOAD16(Ab + (size_t)64 * K + (k0),  &As[buf][w * 16 + 64][0]); \
        GLOAD16(Bb + (k0),                   &Bs[buf][w * 16][0]); \
        GLOAD16(Bb + (size_t)64 * K + (k0),  &Bs[buf][w * 16 + 64][0]); \
        GLOAD16(Bb + (size_t)128 * K + (k0), &Bs[buf][w * 16 + 128][0]); \
        GLOAD16(Bb + (size_t)192 * K + (k0), &Bs[buf][w * 16 + 192][0]); \
    } while (0)

    STAGE(0, 0);
    __syncthreads();
    int buf = 0;
    for (int k0 = 0; k0 < K; k0 += 32, buf ^= 1) {
        if (k0 + 32 < K) STAGE(buf ^ 1, k0 + 32);
        bf16x8 af[4], bfr[8];
#pragma unroll
        for (int t = 0; t < 4; ++t) af[t]  = *(const bf16x8*)(&As[buf][mblk + t * 16 + i16][q4 * 8]);
#pragma unroll
        for (int t = 0; t < 8; ++t) bfr[t] = *(const bf16x8*)(&Bs[buf][nblk + t * 16 + i16][q4 * 8]);
#pragma unroll
        for (int ct = 0; ct < 8; ++ct)
#pragma unroll
            for (int st = 0; st < 4; ++st)
                acc[ct][st] = __builtin_amdgcn_mfma_f32_16x16x32_bf16(bfr[ct], af[st], acc[ct][st], 0, 0, 0);
        __syncthreads();
    }
#undef STAGE

    int region = col0 / DMODEL;
    int cbase = col0 - region * DMODEL + nblk;

    if (region < 2) {
        const float* bias = region ? bk : bq;
        bf16* dstb = region ? Kb : Qb;
#pragma unroll
        for (int ct = 0; ct < 8; ++ct) {
#pragma unroll
            for (int st = 0; st < 4; ++st) {
                int c0 = cbase + ct * 16 + q4 * 4;
                int h = c0 >> 6, d0 = c0 & 63;
                int sg = row0 + mblk + st * 16 + i16;
                int b = sg >> 11, s = sg & 2047;
                float4 bb = *(const float4*)(bias + c0);
                bf16x4 o;
                if (region == 0) {
                    o[0] = (bf16)((acc[ct][st][0] + bb.x) * 0.0225421217f);  // (1/64)*log2(e)
                    o[1] = (bf16)((acc[ct][st][1] + bb.y) * 0.0225421217f);
                    o[2] = (bf16)((acc[ct][st][2] + bb.z) * 0.0225421217f);
                    o[3] = (bf16)((acc[ct][st][3] + bb.w) * 0.0225421217f);
                } else {
                    o[0] = (bf16)(acc[ct][st][0] + bb.x);
                    o[1] = (bf16)(acc[ct][st][1] + bb.y);
                    o[2] = (bf16)(acc[ct][st][2] + bb.z);
                    o[3] = (bf16)(acc[ct][st][3] + bb.w);
                }
                *(bf16x4*)(dstb + (((size_t)(b * HEADS + h)) * SLEN + s) * 64 + d0) = o;
            }
        }
    } else {
        f16 (*Cs)[132] = (f16(*)[132])smem;
#pragma unroll
        for (int p = 0; p < 2; ++p) {
            if ((w >> 1) == p) {
#pragma unroll
                for (int ct = 0; ct < 8; ++ct) {
#pragma unroll
                    for (int st = 0; st < 4; ++st) {
                        int cg = cbase + ct * 16 + q4 * 4;
                        float4 bb = *(const float4*)(bv + cg);
                        f16x4 vv;
                        vv[0] = (f16)(acc[ct][st][0] + bb.x);
                        vv[1] = (f16)(acc[ct][st][1] + bb.y);
                        vv[2] = (f16)(acc[ct][st][2] + bb.z);
                        vv[3] = (f16)(acc[ct][st][3] + bb.w);
                        *(f16x4*)(&Cs[mblk + st * 16 + i16][ct * 16 + q4 * 4]) = vv;
                    }
                }
            }
            __syncthreads();
            int cl = lane * 2;
            int cg = (col0 - 2 * DMODEL) + p * 128 + cl;
            int h = cg >> 6, d = cg & 63;
            int s0 = w * 32;
            int b = row0 >> 11, sg = (row0 & 2047) + s0;
            f16* dst0 = VTb + ((size_t)(b * HEADS + h) * 64 + d) * SLEN + sg;
            f16* dst1 = dst0 + SLEN;
#pragma unroll
            for (int j = 0; j < 4; ++j) {
                unsigned v[8];
#pragma unroll
                for (int i = 0; i < 8; ++i) v[i] = *(const unsigned*)(&Cs[s0 + j * 8 + i][cl]);
                unsigned lo[4], hi[4];
#pragma unroll
                for (int i = 0; i < 4; ++i) {
                    lo[i] = (v[2 * i] & 0xffffu) | (v[2 * i + 1] << 16);
                    hi[i] = (v[2 * i] >> 16) | (v[2 * i + 1] & 0xffff0000u);
                }
                *(uint4*)(dst0 + j * 8) = *(uint4*)lo;
                *(uint4*)(dst1 + j * 8) = *(uint4*)hi;
            }
            __syncthreads();
        }
    }
}

// ---------------- output projection GEMM (128x128, C^T, float4 stores) ----------------
__global__ __launch_bounds__(256, 3) void gemm_out(
    const bf16* __restrict__ A, const bf16* __restrict__ Bw,
    const float* __restrict__ bo, float* __restrict__ out)
{
    __shared__ bf16 As[2][128][32];
    __shared__ bf16 Bs[2][128][32];
    const int K = DMODEL;
    int tid = threadIdx.x;
    int w = tid >> 6, lane = tid & 63, i16 = lane & 15, q4 = lane >> 4;
    int mblk = (w & 1) * 64, nblk = (w >> 1) * 64;
    int row0 = blockIdx.y * 128, col0 = blockIdx.x * 128;
    int srow = (lane >> 2), scol = (lane & 3) * 8;
    f32x4 acc[4][4] = {};

    const bf16* Ab = A  + (size_t)(row0 + w * 16 + srow) * K + scol;
    const bf16* Bb = Bw + (size_t)(col0 + w * 16 + srow) * K + scol;

#define STAGE(buf, k0) do { \
        GLOAD16(Ab + (k0),                  &As[buf][w * 16][0]); \
        GLOAD16(Ab + (size_t)64 * K + (k0), &As[buf][w * 16 + 64][0]); \
        GLOAD16(Bb + (k0),                  &Bs[buf][w * 16][0]); \
        GLOAD16(Bb + (size_t)64 * K + (k0), &Bs[buf][w * 16 + 64][0]); \
    } while (0)

    STAGE(0, 0);
    __syncthreads();
    int buf = 0;
    for (int k0 = 0; k0 < K; k0 += 32, buf ^= 1) {
        if (k0 + 32 < K) STAGE(buf ^ 1, k0 + 32);
        bf16x8 af[4], bfr[4];
#pragma unroll
        for (int t = 0; t < 4; ++t) af[t] = *(const bf16x8*)(&As[buf][mblk + t * 16 + i16][q4 * 8]);
#pragma unroll
        for (int t = 0; t < 4; ++t) bfr[t] = *(const bf16x8*)(&Bs[buf][nblk + t * 16 + i16][q4 * 8]);
#pragma unroll
        for (int ct = 0; ct < 4; ++ct)
#pragma unroll
            for (int st = 0; st < 4; ++st)
                acc[ct][st] = __builtin_amdgcn_mfma_f32_16x16x32_bf16(bfr[ct], af[st], acc[ct][st], 0, 0, 0);
        __syncthreads();
    }
#undef STAGE

#pragma unroll
    for (int ct = 0; ct < 4; ++ct) {
#pragma unroll
        for (int st = 0; st < 4; ++st) {
            int c0 = col0 + nblk + ct * 16 + q4 * 4;
            int s = row0 + mblk + st * 16 + i16;
            float4 bb = *(const float4*)(bo + c0);
            float4 o = {acc[ct][st][0] + bb.x, acc[ct][st][1] + bb.y,
                        acc[ct][st][2] + bb.z, acc[ct][st][3] + bb.w};
            *(float4*)(out + (size_t)s * DMODEL + c0) = o;
        }
    }
}

// ---------------- flash attention v7 ----------------
// R5 structure (32 q/wave, grid 768 = 3 blocks/CU) with:
//  - global_load_lds staging, unpadded XOR-swizzled K/V tiles (chunk ^= row)
//  - l-sum via MFMA against constant ones-fragment (zero LDS, zero VALU adds)
//  - packed cvt_pkrtz f32->f16
__global__ __launch_bounds__(256, 3) void attn_kernel(
    const bf16* __restrict__ Qb, const bf16* __restrict__ Kb,
    const f16* __restrict__ VTb, bf16* __restrict__ att)
{
    __shared__ bf16 Ks[128][64];   // [key][d] swizzled: phys 16B-chunk = c ^ (key&7)
    __shared__ f16  Vt[64][128];   // [d][key] swizzled: phys 16B-chunk = c ^ (d&15)

    int tid = threadIdx.x;
    int w = tid >> 6, lane = tid & 63, i16 = lane & 15, q4 = lane >> 4;
    int qt = blockIdx.x, h = blockIdx.y, b = blockIdx.z;
    size_t bh = (size_t)b * HEADS + h;
    const bf16* Qp = Qb + (bh * SLEN + qt * 128 + w * 32) * 64;
    const bf16* Kp = Kb + bh * SLEN * 64;
    const f16*  Vp = VTb + bh * 64 * SLEN;

    bf16x8 aq[2][2];
#pragma unroll
    for (int qs = 0; qs < 2; ++qs) {
        aq[qs][0] = *(const bf16x8*)(Qp + (qs * 16 + i16) * 64 + q4 * 8);
        aq[qs][1] = *(const bf16x8*)(Qp + (qs * 16 + i16) * 64 + 32 + q4 * 8);
    }

    // per-lane DMA source pointers (swizzled); advance per kt
    int rlK = lane >> 3;
    int cK = (lane & 7) ^ rlK;
    const bf16* kp[4];
#pragma unroll
    for (int j = 0; j < 4; ++j)
        kp[j] = Kp + (size_t)(w * 32 + j * 8 + rlK) * 64 + cK * 8;
    int rlV = lane >> 4;
    const f16* vp[4];
#pragma unroll
    for (int j = 0; j < 4; ++j) {
        int rowa = w * 16 + j * 4 + rlV;
        int cV = (lane & 15) ^ (rowa & 15);
        vp[j] = Vp + (size_t)rowa * SLEN + cV * 8;
    }

    // constant ones A-fragment: A[m][k] = (m==0) -> C row 0 = sum over k of B = l
    f16x4 vones = {};
    if (i16 == 0) { vones[0] = (f16)1; vones[1] = (f16)1; vones[2] = (f16)1; vones[3] = (f16)1; }

    f32x4 oacc[2][4] = {};
    f32x4 lacc[2] = {};
    int ck0 = (q4 ^ (i16 & 7)) * 8;      // swizzled elem offset, chunk q4
    int ck1 = ((q4 ^ 4) ^ (i16 & 7)) * 8;
    int q4h = q4 >> 1, q4l = (q4 & 1) * 4;

    for (int kt = 0; kt < 16; ++kt) {
#pragma unroll
        for (int j = 0; j < 4; ++j) {
            GLOAD16(kp[j], &Ks[w * 32 + j * 8][0]);
            GLOAD16(vp[j], &Vt[w * 16 + j * 4][0]);
            kp[j] += 128 * 64;
            vp[j] += 128;
        }
        __syncthreads();   // drains DMA (vmcnt) + protects prior reads

#pragma unroll
        for (int t = 0; t < 8; ++t) {
            bf16x8 kf0 = *(const bf16x8*)(&Ks[t * 16 + i16][ck0]);
            bf16x8 kf1 = *(const bf16x8*)(&Ks[t * 16 + i16][ck1]);
            f16x4 pf[2];
#pragma unroll
            for (int qs = 0; qs < 2; ++qs) {
                f32x4 z = {};
                z = __builtin_amdgcn_mfma_f32_16x16x32_bf16(kf0, aq[qs][0], z, 0, 0, 0);
                z = __builtin_amdgcn_mfma_f32_16x16x32_bf16(kf1, aq[qs][1], z, 0, 0, 0);
                f16x2 p01 = __builtin_bit_cast(f16x2,
                    __builtin_amdgcn_cvt_pkrtz(__builtin_amdgcn_exp2f(z[0]),
                                               __builtin_amdgcn_exp2f(z[1])));
                f16x2 p23 = __builtin_bit_cast(f16x2,
                    __builtin_amdgcn_cvt_pkrtz(__builtin_amdgcn_exp2f(z[2]),
                                               __builtin_amdgcn_exp2f(z[3])));
                pf[qs][0] = p01[0]; pf[qs][1] = p01[1];
                pf[qs][2] = p23[0]; pf[qs][3] = p23[1];
                lacc[qs] = __builtin_amdgcn_mfma_f32_16x16x16f16(vones, pf[qs], lacc[qs], 0, 0, 0);
            }
#pragma unroll
            for (int dt = 0; dt < 4; ++dt) {
                int vc = ((2 * t + q4h) ^ i16) * 8 + q4l;
                f16x4 vf = *(const f16x4*)(&Vt[dt * 16 + i16][vc]);
                oacc[0][dt] = __builtin_amdgcn_mfma_f32_16x16x16f16(vf, pf[0], oacc[0][dt], 0, 0, 0);
                oacc[1][dt] = __builtin_amdgcn_mfma_f32_16x16x16f16(vf, pf[1], oacc[1][dt], 0, 0, 0);
            }
        }
        __syncthreads();   // reads done before next kt's DMA overwrites
    }

#pragma unroll
    for (int qs = 0; qs < 2; ++qs) {
        float l = __shfl(lacc[qs][0], i16);   // row 0 of l-tile lives in lanes 0..15
        float inv = 1.f / l;
        int row = qt * 128 + w * 32 + qs * 16 + i16;
        size_t obase = ((size_t)b * SLEN + row) * DMODEL + h * 64;
#pragma unroll
        for (int dt = 0; dt < 4; ++dt) {
            bf16x4 o;
#pragma unroll
            for (int r = 0; r < 4; ++r) o[r] = (bf16)(oacc[qs][dt][r] * inv);
            *(bf16x4*)(att + obase + dt * 16 + q4 * 4) = o;
        }
    }
}

// ---------------- launch ----------------
extern "C" void kernel_launch(void* const* d_in, const int* in_sizes, int n_in,
                              void* d_out, int out_size, void* d_ws, size_t ws_size,
                              hipStream_t stream) {
    const float* x  = (const float*)d_in[0];
    const float* Wq = (const float*)d_in[1];
    const float* bq = (const float*)d_in[2];
    const float* Wk = (const float*)d_in[3];
    const float* bk = (const float*)d_in[4];
    const float* Wv = (const float*)d_in[5];
    const float* bv = (const float*)d_in[6];
    const float* Wo = (const float*)d_in[7];
    const float* bo = (const float*)d_in[8];
    float* out = (float*)d_out;

    char* ws = (char*)d_ws;
    bf16* xb   = (bf16*)(ws);
    bf16* wqkv = (bf16*)(ws + 12582912);   // Wq|Wk|Wv, then Wo contiguous
    bf16* wob  = (bf16*)(ws + 16121856);
    bf16* Qb   = (bf16*)(ws + 17301504);
    bf16* Kb   = (bf16*)(ws + 29884416);
    f16*  VTb  = (f16*)(ws + 42467328);
    bf16* attb = xb;  // xb dead after gemm_qkv; reuse for attention output

    cvt_all<<<8448, 256, 0, stream>>>(x, Wq, Wk, Wv, Wo, xb, wqkv);
    gemm_qkv<<<dim3(9, 64), 256, 0, stream>>>(xb, wqkv, bq, bk, bv, Qb, Kb, VTb);
    attn_kernel<<<dim3(16, 12, 4), 256, 0, stream>>>(Qb, Kb, VTb, attb);
    gemm_out<<<dim3(6, 64), 256, 0, stream>>>(attb, wob, bo, out);
}

// Round 9
// 229.333 us; speedup vs baseline: 1.1645x; 1.0226x over previous
//
#include <hip/hip_runtime.h>
#include <hip/hip_bf16.h>

typedef __bf16 bf16;
typedef _Float16 f16;
typedef bf16 bf16x8 __attribute__((ext_vector_type(8)));
typedef bf16 bf16x4 __attribute__((ext_vector_type(4)));
typedef f16 f16x8 __attribute__((ext_vector_type(8)));
typedef f16 f16x4 __attribute__((ext_vector_type(4)));
typedef f16 f16x2 __attribute__((ext_vector_type(2)));
typedef float f32x4 __attribute__((ext_vector_type(4)));

#define SLEN 2048
#define HEADS 12
#define DMODEL 768

// async global->LDS, 16B per lane; lds base must be wave-uniform (HW scatters lane*16)
#define GLOAD16(g, l) \
    __builtin_amdgcn_global_load_lds((const __attribute__((address_space(1))) void*)(g), \
                                     (__attribute__((address_space(3))) void*)(l), 16, 0, 0)

// ---------------- fused fp32 -> bf16 convert (x + all 4 weights, one launch) ----------------
__global__ void cvt_all(const float* __restrict__ x,
                        const float* __restrict__ Wq, const float* __restrict__ Wk,
                        const float* __restrict__ Wv, const float* __restrict__ Wo,
                        bf16* __restrict__ xb, bf16* __restrict__ wdst) {
    int idx = blockIdx.x * 256 + threadIdx.x;
    const float* s; bf16* d;
    if (idx < 1572864) {
        s = x; d = xb;
    } else {
        int t = idx - 1572864;
        int wi = t / 147456;          // 0..3 (block-uniform: boundaries on 576-block lines)
        idx = t - wi * 147456;
        s = (wi == 0) ? Wq : (wi == 1) ? Wk : (wi == 2) ? Wv : Wo;
        d = wdst + (size_t)wi * 589824;
    }
    float4 v = ((const float4*)s)[idx];
    bf16x4 o;
    o[0] = (bf16)v.x; o[1] = (bf16)v.y; o[2] = (bf16)v.z; o[3] = (bf16)v.w;
    *(bf16x4*)(d + (size_t)idx * 4) = o;
}

// ---------------- QKV projection GEMM: 128x256 block, 64x128 wave tile ----------------
__global__ __launch_bounds__(256, 2) void gemm_qkv(
    const bf16* __restrict__ A, const bf16* __restrict__ Bw,
    const float* __restrict__ bq, const float* __restrict__ bk, const float* __restrict__ bv,
    bf16* __restrict__ Qb, bf16* __restrict__ Kb, f16* __restrict__ VTb)
{
    __shared__ __align__(16) char smem[49152];
    typedef bf16 ATile[128][32];
    typedef bf16 BTile[256][32];
    ATile* As = (ATile*)smem;
    BTile* Bs = (BTile*)(smem + 16384);
    const int K = DMODEL;
    int tid = threadIdx.x;
    int w = tid >> 6, lane = tid & 63, i16 = lane & 15, q4 = lane >> 4;
    int mblk = (w & 1) * 64, nblk = (w >> 1) * 128;
    int row0 = blockIdx.y * 128, col0 = blockIdx.x * 256;
    int srow = lane >> 2, scol = (lane & 3) * 8;
    f32x4 acc[8][4] = {};

    const bf16* Ab = A  + (size_t)(row0 + w * 16 + srow) * K + scol;
    const bf16* Bb = Bw + (size_t)(col0 + w * 16 + srow) * K + scol;

#define STAGE(buf, k0) do { \
        GLOAD16(Ab + (k0),                   &As[buf][w * 16][0]); \
        GLOAD16(Ab + (size_t)64 * K + (k0),  &As[buf][w * 16 + 64][0]); \
        GLOAD16(Bb + (k0),                   &Bs[buf][w * 16][0]); \
        GLOAD16(Bb + (size_t)64 * K + (k0),  &Bs[buf][w * 16 + 64][0]); \
        GLOAD16(Bb + (size_t)128 * K + (k0), &Bs[buf][w * 16 + 128][0]); \
        GLOAD16(Bb + (size_t)192 * K + (k0), &Bs[buf][w * 16 + 192][0]); \
    } while (0)

    STAGE(0, 0);
    __syncthreads();
    int buf = 0;
    for (int k0 = 0; k0 < K; k0 += 32, buf ^= 1) {
        if (k0 + 32 < K) STAGE(buf ^ 1, k0 + 32);
        bf16x8 af[4], bfr[8];
#pragma unroll
        for (int t = 0; t < 4; ++t) af[t]  = *(const bf16x8*)(&As[buf][mblk + t * 16 + i16][q4 * 8]);
#pragma unroll
        for (int t = 0; t < 8; ++t) bfr[t] = *(const bf16x8*)(&Bs[buf][nblk + t * 16 + i16][q4 * 8]);
#pragma unroll
        for (int ct = 0; ct < 8; ++ct)
#pragma unroll
            for (int st = 0; st < 4; ++st)
                acc[ct][st] = __builtin_amdgcn_mfma_f32_16x16x32_bf16(bfr[ct], af[st], acc[ct][st], 0, 0, 0);
        __syncthreads();
    }
#undef STAGE

    int region = col0 / DMODEL;
    int cbase = col0 - region * DMODEL + nblk;

    if (region < 2) {
        const float* bias = region ? bk : bq;
        bf16* dstb = region ? Kb : Qb;
#pragma unroll
        for (int ct = 0; ct < 8; ++ct) {
#pragma unroll
            for (int st = 0; st < 4; ++st) {
                int c0 = cbase + ct * 16 + q4 * 4;
                int h = c0 >> 6, d0 = c0 & 63;
                int sg = row0 + mblk + st * 16 + i16;
                int b = sg >> 11, s = sg & 2047;
                float4 bb = *(const float4*)(bias + c0);
                bf16x4 o;
                if (region == 0) {
                    o[0] = (bf16)((acc[ct][st][0] + bb.x) * 0.0225421217f);  // (1/64)*log2(e)
                    o[1] = (bf16)((acc[ct][st][1] + bb.y) * 0.0225421217f);
                    o[2] = (bf16)((acc[ct][st][2] + bb.z) * 0.0225421217f);
                    o[3] = (bf16)((acc[ct][st][3] + bb.w) * 0.0225421217f);
                } else {
                    o[0] = (bf16)(acc[ct][st][0] + bb.x);
                    o[1] = (bf16)(acc[ct][st][1] + bb.y);
                    o[2] = (bf16)(acc[ct][st][2] + bb.z);
                    o[3] = (bf16)(acc[ct][st][3] + bb.w);
                }
                *(bf16x4*)(dstb + (((size_t)(b * HEADS + h)) * SLEN + s) * 64 + d0) = o;
            }
        }
    } else {
        f16 (*Cs)[132] = (f16(*)[132])smem;
#pragma unroll
        for (int p = 0; p < 2; ++p) {
            if ((w >> 1) == p) {
#pragma unroll
                for (int ct = 0; ct < 8; ++ct) {
#pragma unroll
                    for (int st = 0; st < 4; ++st) {
                        int cg = cbase + ct * 16 + q4 * 4;
                        float4 bb = *(const float4*)(bv + cg);
                        f16x4 vv;
                        vv[0] = (f16)(acc[ct][st][0] + bb.x);
                        vv[1] = (f16)(acc[ct][st][1] + bb.y);
                        vv[2] = (f16)(acc[ct][st][2] + bb.z);
                        vv[3] = (f16)(acc[ct][st][3] + bb.w);
                        *(f16x4*)(&Cs[mblk + st * 16 + i16][ct * 16 + q4 * 4]) = vv;
                    }
                }
            }
            __syncthreads();
            int cl = lane * 2;
            int cg = (col0 - 2 * DMODEL) + p * 128 + cl;
            int h = cg >> 6, d = cg & 63;
            int s0 = w * 32;
            int b = row0 >> 11, sg = (row0 & 2047) + s0;
            f16* dst0 = VTb + ((size_t)(b * HEADS + h) * 64 + d) * SLEN + sg;
            f16* dst1 = dst0 + SLEN;
#pragma unroll
            for (int j = 0; j < 4; ++j) {
                unsigned v[8];
#pragma unroll
                for (int i = 0; i < 8; ++i) v[i] = *(const unsigned*)(&Cs[s0 + j * 8 + i][cl]);
                unsigned lo[4], hi[4];
#pragma unroll
                for (int i = 0; i < 4; ++i) {
                    lo[i] = (v[2 * i] & 0xffffu) | (v[2 * i + 1] << 16);
                    hi[i] = (v[2 * i] >> 16) | (v[2 * i + 1] & 0xffff0000u);
                }
                *(uint4*)(dst0 + j * 8) = *(uint4*)lo;
                *(uint4*)(dst1 + j * 8) = *(uint4*)hi;
            }
            __syncthreads();
        }
    }
}

// ---------------- output projection GEMM: 128x64 blocks, grid 768 = 3/CU ----------------
// R8 had 384 blocks at 3-resident -> 2:1 CU imbalance (~2x balanced time). 768 fixes it.
__global__ __launch_bounds__(256, 3) void gemm_out(
    const bf16* __restrict__ A, const bf16* __restrict__ Bw,
    const float* __restrict__ bo, float* __restrict__ out)
{
    __shared__ bf16 As[2][128][32];
    __shared__ bf16 Bs[2][64][32];
    const int K = DMODEL;
    int tid = threadIdx.x;
    int w = tid >> 6, lane = tid & 63, i16 = lane & 15, q4 = lane >> 4;
    int row0 = blockIdx.y * 128, col0 = blockIdx.x * 64;
    int srow = (lane >> 2), scol = (lane & 3) * 8;
    f32x4 acc[4][2] = {};   // C^T: 4 col-tiles x 2 row-tiles (wave = 32 rows x 64 cols)

    const bf16* Ab = A  + (size_t)(row0 + w * 16 + srow) * K + scol;
    const bf16* Bb = Bw + (size_t)(col0 + w * 16 + srow) * K + scol;

#define STAGE(buf, k0) do { \
        GLOAD16(Ab + (k0),                  &As[buf][w * 16][0]); \
        GLOAD16(Ab + (size_t)64 * K + (k0), &As[buf][w * 16 + 64][0]); \
        GLOAD16(Bb + (k0),                  &Bs[buf][w * 16][0]); \
    } while (0)

    STAGE(0, 0);
    __syncthreads();
    int buf = 0;
    for (int k0 = 0; k0 < K; k0 += 32, buf ^= 1) {
        if (k0 + 32 < K) STAGE(buf ^ 1, k0 + 32);
        bf16x8 af[2], bfr[4];
#pragma unroll
        for (int t = 0; t < 2; ++t) af[t] = *(const bf16x8*)(&As[buf][w * 32 + t * 16 + i16][q4 * 8]);
#pragma unroll
        for (int t = 0; t < 4; ++t) bfr[t] = *(const bf16x8*)(&Bs[buf][t * 16 + i16][q4 * 8]);
#pragma unroll
        for (int ct = 0; ct < 4; ++ct)
#pragma unroll
            for (int st = 0; st < 2; ++st)
                acc[ct][st] = __builtin_amdgcn_mfma_f32_16x16x32_bf16(bfr[ct], af[st], acc[ct][st], 0, 0, 0);
        __syncthreads();
    }
#undef STAGE

#pragma unroll
    for (int ct = 0; ct < 4; ++ct) {
#pragma unroll
        for (int st = 0; st < 2; ++st) {
            int c0 = col0 + ct * 16 + q4 * 4;
            int s = row0 + w * 32 + st * 16 + i16;
            float4 bb = *(const float4*)(bo + c0);
            float4 o = {acc[ct][st][0] + bb.x, acc[ct][st][1] + bb.y,
                        acc[ct][st][2] + bb.z, acc[ct][st][3] + bb.w};
            *(float4*)(out + (size_t)s * DMODEL + c0) = o;
        }
    }
}

// ---------------- flash attention v8: K=32 PV via permuted-key LDS ----------------
// K-tile phys slot s holds logical key 32*(s>>5) + 8*((s>>2)&3) + 4*((s>>4)&1) + (s&3)
// (permutation applied in DMA source addr — free). Two consecutive score tiles then
// give each lane keys 8*q4..8*q4+7 = exact B-layout of mfma_f32_16x16x32_f16:
// PV 64 K=16 MFMAs -> 32 K=32, l-sum 16 -> 8 (−36% MFMA pipe demand).
__global__ __launch_bounds__(256, 3) void attn_kernel(
    const bf16* __restrict__ Qb, const bf16* __restrict__ Kb,
    const f16* __restrict__ VTb, bf16* __restrict__ att)
{
    __shared__ bf16 Ks[128][64];   // permuted keys, chunk swizzle c ^= (row&7)
    __shared__ f16  Vt[64][128];   // [d][key] logical order, chunk swizzle c ^= (d&15)

    int tid = threadIdx.x;
    int w = tid >> 6, lane = tid & 63, i16 = lane & 15, q4 = lane >> 4;
    int qt = blockIdx.x, h = blockIdx.y, b = blockIdx.z;
    size_t bh = (size_t)b * HEADS + h;
    const bf16* Qp = Qb + (bh * SLEN + qt * 128 + w * 32) * 64;
    const bf16* Kp = Kb + bh * SLEN * 64;
    const f16*  Vp = VTb + bh * 64 * SLEN;

    bf16x8 aq[2][2];
#pragma unroll
    for (int qs = 0; qs < 2; ++qs) {
        aq[qs][0] = *(const bf16x8*)(Qp + (qs * 16 + i16) * 64 + q4 * 8);
        aq[qs][1] = *(const bf16x8*)(Qp + (qs * 16 + i16) * 64 + 32 + q4 * 8);
    }

    // K DMA: phys row p gets logical key kappa(p); source addr carries both the
    // permutation and the chunk swizzle.
    int rlK = lane >> 3;
    int cK = (lane & 7) ^ rlK;
    const bf16* kp[4];
#pragma unroll
    for (int j = 0; j < 4; ++j) {
        int p = w * 32 + j * 8 + rlK;
        int key = 32 * (p >> 5) + 8 * ((p >> 2) & 3) + 4 * ((p >> 4) & 1) + (p & 3);
        kp[j] = Kp + (size_t)key * 64 + cK * 8;
    }
    int rlV = lane >> 4;
    const f16* vp[4];
#pragma unroll
    for (int j = 0; j < 4; ++j) {
        int rowa = w * 16 + j * 4 + rlV;
        int cV = (lane & 15) ^ (rowa & 15);
        vp[j] = Vp + (size_t)rowa * SLEN + cV * 8;
    }

    // ones A-frag for K=32: A[0][k]=1 -> lanes i16==0 hold 8 ones
    f16x8 vones = {};
    if (i16 == 0)
#pragma unroll
        for (int j = 0; j < 8; ++j) vones[j] = (f16)1;

    f32x4 oacc[2][4] = {};
    f32x4 lacc[2] = {};
    int ck0 = (q4 ^ (i16 & 7)) * 8;
    int ck1 = ((q4 ^ 4) ^ (i16 & 7)) * 8;

    for (int kt = 0; kt < 16; ++kt) {
#pragma unroll
        for (int j = 0; j < 4; ++j) {
            GLOAD16(kp[j], &Ks[w * 32 + j * 8][0]);
            GLOAD16(vp[j], &Vt[w * 16 + j * 4][0]);
            kp[j] += 128 * 64;
            vp[j] += 128;
        }
        __syncthreads();   // drains DMA + protects prior reads

#pragma unroll
        for (int u = 0; u < 4; ++u) {        // 4 key-groups of 32
            bf16x8 k00 = *(const bf16x8*)(&Ks[u * 32 + i16][ck0]);
            bf16x8 k01 = *(const bf16x8*)(&Ks[u * 32 + i16][ck1]);
            bf16x8 k10 = *(const bf16x8*)(&Ks[u * 32 + 16 + i16][ck0]);
            bf16x8 k11 = *(const bf16x8*)(&Ks[u * 32 + 16 + i16][ck1]);
            f16x8 pf[2];
#pragma unroll
            for (int qs = 0; qs < 2; ++qs) {
                f32x4 z0 = {}, z1 = {};
                z0 = __builtin_amdgcn_mfma_f32_16x16x32_bf16(k00, aq[qs][0], z0, 0, 0, 0);
                z0 = __builtin_amdgcn_mfma_f32_16x16x32_bf16(k01, aq[qs][1], z0, 0, 0, 0);
                z1 = __builtin_amdgcn_mfma_f32_16x16x32_bf16(k10, aq[qs][0], z1, 0, 0, 0);
                z1 = __builtin_amdgcn_mfma_f32_16x16x32_bf16(k11, aq[qs][1], z1, 0, 0, 0);
                f16x2 p01 = __builtin_bit_cast(f16x2,
                    __builtin_amdgcn_cvt_pkrtz(__builtin_amdgcn_exp2f(z0[0]),
                                               __builtin_amdgcn_exp2f(z0[1])));
                f16x2 p23 = __builtin_bit_cast(f16x2,
                    __builtin_amdgcn_cvt_pkrtz(__builtin_amdgcn_exp2f(z0[2]),
                                               __builtin_amdgcn_exp2f(z0[3])));
                f16x2 p45 = __builtin_bit_cast(f16x2,
                    __builtin_amdgcn_cvt_pkrtz(__builtin_amdgcn_exp2f(z1[0]),
                                               __builtin_amdgcn_exp2f(z1[1])));
                f16x2 p67 = __builtin_bit_cast(f16x2,
                    __builtin_amdgcn_cvt_pkrtz(__builtin_amdgcn_exp2f(z1[2]),
                                               __builtin_amdgcn_exp2f(z1[3])));
                pf[qs][0] = p01[0]; pf[qs][1] = p01[1];
                pf[qs][2] = p23[0]; pf[qs][3] = p23[1];
                pf[qs][4] = p45[0]; pf[qs][5] = p45[1];
                pf[qs][6] = p67[0]; pf[qs][7] = p67[1];
                lacc[qs] = __builtin_amdgcn_mfma_f32_16x16x32_f16(vones, pf[qs], lacc[qs], 0, 0, 0);
            }
#pragma unroll
            for (int dt = 0; dt < 4; ++dt) {
                int vc = ((4 * u + q4) ^ i16) * 8;
                f16x8 vf = *(const f16x8*)(&Vt[dt * 16 + i16][vc]);
                oacc[0][dt] = __builtin_amdgcn_mfma_f32_16x16x32_f16(vf, pf[0], oacc[0][dt], 0, 0, 0);
                oacc[1][dt] = __builtin_amdgcn_mfma_f32_16x16x32_f16(vf, pf[1], oacc[1][dt], 0, 0, 0);
            }
        }
        __syncthreads();   // reads done before next kt's DMA overwrites
    }

#pragma unroll
    for (int qs = 0; qs < 2; ++qs) {
        float l = __shfl(lacc[qs][0], i16);   // row 0 of l-tile lives in lanes 0..15
        float inv = 1.f / l;
        int row = qt * 128 + w * 32 + qs * 16 + i16;
        size_t obase = ((size_t)b * SLEN + row) * DMODEL + h * 64;
#pragma unroll
        for (int dt = 0; dt < 4; ++dt) {
            bf16x4 o;
#pragma unroll
            for (int r = 0; r < 4; ++r) o[r] = (bf16)(oacc[qs][dt][r] * inv);
            *(bf16x4*)(att + obase + dt * 16 + q4 * 4) = o;
        }
    }
}

// ---------------- launch ----------------
extern "C" void kernel_launch(void* const* d_in, const int* in_sizes, int n_in,
                              void* d_out, int out_size, void* d_ws, size_t ws_size,
                              hipStream_t stream) {
    const float* x  = (const float*)d_in[0];
    const float* Wq = (const float*)d_in[1];
    const float* bq = (const float*)d_in[2];
    const float* Wk = (const float*)d_in[3];
    const float* bk = (const float*)d_in[4];
    const float* Wv = (const float*)d_in[5];
    const float* bv = (const float*)d_in[6];
    const float* Wo = (const float*)d_in[7];
    const float* bo = (const float*)d_in[8];
    float* out = (float*)d_out;

    char* ws = (char*)d_ws;
    bf16* xb   = (bf16*)(ws);
    bf16* wqkv = (bf16*)(ws + 12582912);   // Wq|Wk|Wv, then Wo contiguous
    bf16* wob  = (bf16*)(ws + 16121856);
    bf16* Qb   = (bf16*)(ws + 17301504);
    bf16* Kb   = (bf16*)(ws + 29884416);
    f16*  VTb  = (f16*)(ws + 42467328);
    bf16* attb = xb;  // xb dead after gemm_qkv; reuse for attention output

    cvt_all<<<8448, 256, 0, stream>>>(x, Wq, Wk, Wv, Wo, xb, wqkv);
    gemm_qkv<<<dim3(9, 64), 256, 0, stream>>>(xb, wqkv, bq, bk, bv, Qb, Kb, VTb);
    attn_kernel<<<dim3(16, 12, 4), 256, 0, stream>>>(Qb, Kb, VTb, attb);
    gemm_out<<<dim3(12, 64), 256, 0, stream>>>(attb, wob, bo, out);
}